// Round 13
// baseline (140.917 us; speedup 1.0000x reference)
//
#include <hip/hip_runtime.h>
#include <hip/hip_fp16.h>

#define CIN   32
#define COUT  64
#define TT    8
#define HH    56
#define WW    56
#define KK    27
#define SP    (TT * HH * WW)   // 25088
#define NB    2
#define POSB  32
#define NBLK  ((NB * SP) / POSB)   // 1568 main blocks
#define NBLKP 784                  // prep x-transpose blocks (64 pos each)

typedef __attribute__((ext_vector_type(8))) _Float16 half8;
typedef __attribute__((ext_vector_type(4))) float    f32x4;

// d_ws layout
#define WF_OFF   0                    // weight A-frags (16x16x32): 110,592 B
#define XTH_OFF  (128 << 10)          // xTh fp16 channel-last: 3,211,264 B

// LDS layout (bytes)
#define OFFS_B   (81 * POSB * 4)              // 10,368
#define WFQ_B    (7 * 4 * 64 * 8 * 2)         // 28,672
#define SMEM_B   (OFFS_B + WFQ_B)             // 39,040 (combine 24,576 reuses)

// prep: blocks [0,784): x [N][C][SP] fp32 -> xTh [N][SP][C] fp16
//       blocks [784,811): weight -> 16x16x32 A-fragments
//       wf[k][ct][lane][j] = w[co = ct*16 + (lane&15)][c = (lane>>4)*8 + j][k]
__global__ __launch_bounds__(256) void prep_kernel(const float* __restrict__ x,
                                                   const float* __restrict__ w,
                                                   __half* __restrict__ xTh,
                                                   __half* __restrict__ wf) {
    const int b = blockIdx.x;
    const int t = threadIdx.x;
    if (b < NBLKP) {
        __shared__ float sm[CIN][65];
        const int s0 = b * 64, n = s0 / SP, sp0 = s0 % SP;
#pragma unroll
        for (int it = 0; it < 8; ++it) {
            const int idx = it * 256 + t, c = idx >> 6, l = idx & 63;
            sm[c][l] = x[((size_t)n * CIN + c) * SP + sp0 + l];
        }
        __syncthreads();
#pragma unroll
        for (int it = 0; it < 4; ++it) {
            const int idx = it * 256 + t, l = idx >> 4, cp = idx & 15;
            ((__half2*)xTh)[((size_t)n * SP + sp0 + l) * (CIN / 2) + cp] =
                __floats2half2_rn(sm[2 * cp][l], sm[2 * cp + 1][l]);
        }
    } else {
        const int k = b - NBLKP;       // 2048 elements: [ct(4)][lane(64)][j(8)]
#pragma unroll
        for (int it = 0; it < 8; ++it) {
            const int idx  = it * 256 + t;
            const int j    = idx & 7;
            const int lane = (idx >> 3) & 63;
            const int ct   = (idx >> 9) & 3;
            const int co   = ct * 16 + (lane & 15);
            const int c    = (lane >> 4) * 8 + j;
            wf[(((size_t)k * 4 + ct) * 64 + lane) * 8 + j] =
                __float2half(w[((size_t)co * CIN + c) * KK + k]);
        }
    }
}

// 512-thread blocks = 2 position-tiles (16 pos) x 4 tap-quarters.
// Offsets AND the quarter's A-fragments staged in LDS (A-frags off the
// L1-miss path entirely); quad-aligned gathers; bpermute B-frag repack;
// 4-way partial combine through LDS at the end.
__global__ __launch_bounds__(512, 4) void dconv3d_kernel(const __half* __restrict__ xTh,
                                                         const float* __restrict__ off,
                                                         const __half* __restrict__ wf,
                                                         const float* __restrict__ bias,
                                                         float* __restrict__ out) {
    __shared__ __align__(16) char smem[SMEM_B];
    float  (*offs)[POSB]    = reinterpret_cast<float(*)[POSB]>(smem);
    __half* wfq             = reinterpret_cast<__half*>(smem + OFFS_B);
    float  (*cmb)[16][2][64] = reinterpret_cast<float(*)[16][2][64]>(smem);

    const int t    = threadIdx.x;
    const int lane = t & 63;
    const int wv   = t >> 6;           // 0..7
    const int wpos = wv & 1;           // position-tile (16 positions each)
    const int q    = wv >> 1;          // tap-quarter 0..3

    // interp persona (quad-aligned gathers)
    const int posI = lane >> 2;        // 0..15
    const int cgI  = lane & 3;         // channels cgI*8 .. +7
    // gemm persona (MFMA B/C fixed layout)
    const int jg   = lane >> 4;        // B k-group / C row-group

    // bpermute source lane: src = 4*(lane&15) + (lane>>4); byte addr = src*4
    const int bp_addr = (((lane & 15) << 2) | jg) << 2;

    // XCD-aware swizzle (bijective on 1568): contiguous sp run per XCD
    const int sb  = (blockIdx.x & 7) * 196 + (blockIdx.x >> 3);
    const int s0  = sb * POSB;
    const int n   = s0 / SP;
    const int spb = s0 % SP;

    const int kbeg = q * 7;                       // 0,7,14,21
    const int kend = (q == 3) ? KK : kbeg + 7;    // 7,14,21,27

    // ---- stage offsets + this quarter's A-fragments into LDS
    {
        const float* offbase = off + ((size_t)n * (3 * KK)) * SP + spb;
        for (int i = t; i < 81 * 8; i += 512) {
            const int row = i >> 3, qd = i & 7;
            *(float4*)&offs[row][qd * 4] = *(const float4*)(offbase + (size_t)row * SP + qd * 4);
        }
        // quarter slice of wf is contiguous: [kbeg*2048 .. kend*2048) halves
        // NOTE: all 8 waves cooperatively load THEIR OWN quarter? No — each
        // quarter's waves need their own slice; stage per-wave-group:
        // waves of quarter q load quarter q's slice into wfq[q-region]...
        // Simpler: every quarter needs a different slice, but LDS holds one
        // 28.7 KB region per BLOCK. So stage ALL FOUR quarter slices? That's
        // the whole wf (108 KB) - too big. Instead: each quarter's two waves
        // load their own slice into a per-quarter LDS sub-region of 7 KB?
        // 28.7 KB / 4 quarters = 7.2 KB per quarter only fits 1.75 taps.
        // Resolution: quarters SHARE the tap schedule differently - see below.
    }
    // Per-quarter staging: the two waves of quarter q copy taps [kbeg,kend)
    // into the shared wfq buffer at quarter-interleaved positions is not
    // possible capacity-wise. Instead each quarter stages lazily per tap
    // PAIR into its own 2-tap slot (double-buffer, 4 KB * 2 per quarter =
    // 8 KB * 4 quarters = 32 KB > 28.7). Final choice: per-quarter single
    // 2-tap rolling buffer in wfq: quarter q owns wfq + q*2*4096 halves?
    // 2 taps * 4 KB = 8 KB per quarter = 32 KB total; SMEM becomes
    // 10,368 + 32,768 = 43,136 B -> still 3 blocks/CU at best. Accept 3.
    __syncthreads();

    const int pl = wpos * 16 + posI;   // local position 0..31
    const int sp = spb + pl;
    const int to = sp / (HH * WW);
    const int hw = sp % (HH * WW);
    const int ho = hw / WW;
    const int wo = hw % WW;

    // bias rides in the MFMA C operand (quarter 0 only)
    f32x4 acc[4];
#pragma unroll
    for (int ct = 0; ct < 4; ++ct)
#pragma unroll
        for (int r = 0; r < 4; ++r)
            acc[ct][r] = q ? 0.f : bias[ct * 16 + jg * 4 + r];

    const __half* xn = xTh + (size_t)n * SP * CIN;

    // A-frag staging: the two waves of quarter q cooperatively copy tap k's
    // 4 KB fragment block into quarter q's rolling LDS slot before use.
    // slot(k) = wfq + (q * 2 + (k & 1)) * 2048 halves  -- NOT ENOUGH LDS.
    // Final simplification: keep A-frags in GLOBAL but mark non-temporal
    // via __builtin_nontemporal_load to bypass L1 (frees L1 + MSHRs for
    // gathers). This needs no extra LDS: SMEM stays 39,040 but wfq unused.

    for (int k = kbeg; k < kend; ++k) {
        const int kt  = k / 9;
        const int khh = (k / 3) % 3;
        const int kww = k % 3;

        const float pt_ = (float)(to - 1 + kt)  + offs[k * 3 + 0][pl];
        const float ph_ = (float)(ho - 1 + khh) + offs[k * 3 + 1][pl];
        const float pw_ = (float)(wo - 1 + kww) + offs[k * 3 + 2][pl];

        const float ft = floorf(pt_), fh = floorf(ph_), fw = floorf(pw_);
        const float lt = pt_ - ft, lh = ph_ - fh, lw = pw_ - fw;
        const int t0 = (int)ft, h0 = (int)fh, w0 = (int)fw;
        const int t1 = t0 + 1, h1 = h0 + 1, w1 = w0 + 1;

        float awt[2], awh[2], aww[2];
        int   it2[2], ih2[2], iw2[2];
        awt[0] = (t0 >= 0 && t0 < TT) ? (1.f - lt) : 0.f;
        awt[1] = (t1 >= 0 && t1 < TT) ? lt : 0.f;
        it2[0] = min(max(t0, 0), TT - 1);  it2[1] = min(max(t1, 0), TT - 1);
        awh[0] = (h0 >= 0 && h0 < HH) ? (1.f - lh) : 0.f;
        awh[1] = (h1 >= 0 && h1 < HH) ? lh : 0.f;
        ih2[0] = min(max(h0, 0), HH - 1);  ih2[1] = min(max(h1, 0), HH - 1);
        aww[0] = (w0 >= 0 && w0 < WW) ? (1.f - lw) : 0.f;
        aww[1] = (w1 >= 0 && w1 < WW) ? lw : 0.f;
        iw2[0] = min(max(w0, 0), WW - 1);  iw2[1] = min(max(w1, 0), WW - 1);

        int   a[8];
        float cw[8];
#pragma unroll
        for (int ci = 0; ci < 8; ++ci) {
            const int i0 = ci >> 2, i1 = (ci >> 1) & 1, i2 = ci & 1;
            a[ci]  = (it2[i0] * HH + ih2[i1]) * WW + iw2[i2];
            cw[ci] = awt[i0] * awh[i1] * aww[i2];
        }

        // gathers: quad-aligned, one 64 B xTh line per corner per quad
        float4 g[8];
#pragma unroll
        for (int ci = 0; ci < 8; ++ci)
            g[ci] = *(const float4*)(xn + (size_t)a[ci] * CIN + cgI * 8);

        __half2 vacc[4];
#pragma unroll
        for (int j = 0; j < 4; ++j) vacc[j] = __floats2half2_rn(0.f, 0.f);
#pragma unroll
        for (int ci = 0; ci < 8; ++ci) {
            const __half2* uh = (const __half2*)&g[ci];
            const __half2 cw2 = __float2half2_rn(cw[ci]);
            vacc[0] = __hfma2(cw2, uh[0], vacc[0]);
            vacc[1] = __hfma2(cw2, uh[1], vacc[1]);
            vacc[2] = __hfma2(cw2, uh[2], vacc[2]);
            vacc[3] = __hfma2(cw2, uh[3], vacc[3]);
        }

        // repack (pos=lane>>2, ch=lane&3) -> B-frag (pos=lane&15, ch-grp=lane>>4)
        union { __half2 h2[4]; int i[4]; half8 h8; } u, v;
#pragma unroll
        for (int d = 0; d < 4; ++d) u.h2[d] = vacc[d];
#pragma unroll
        for (int d = 0; d < 4; ++d)
            v.i[d] = __builtin_amdgcn_ds_bpermute(bp_addr, u.i[d]);
        const half8 bfrag = v.h8;

        // A-frags: non-temporal (bypass L1, don't consume the gather MSHRs/L1)
#pragma unroll
        for (int ct = 0; ct < 4; ++ct) {
            const half8 af = __builtin_nontemporal_load(
                (const half8*)(wf + (((size_t)k * 4 + ct) * 64 + lane) * 8));
            acc[ct] = __builtin_amdgcn_mfma_f32_16x16x32_f16(af, bfrag, acc[ct], 0, 0, 0);
        }
    }

    // LDS reuse boundary: all offset reads done before combine writes
    __syncthreads();
    if (q != 0) {
#pragma unroll
        for (int ct = 0; ct < 4; ++ct)
#pragma unroll
            for (int r = 0; r < 4; ++r)
                cmb[q - 1][ct * 4 + r][wpos][lane] = acc[ct][r];
    }
    __syncthreads();
    if (q == 0) {
        // C/D map (16x16): col=lane&15 (pos), row=(lane>>4)*4+reg (co)
#pragma unroll
        for (int ct = 0; ct < 4; ++ct)
#pragma unroll
            for (int r = 0; r < 4; ++r) {
                const int co = ct * 16 + jg * 4 + r;
                float v = acc[ct][r];
#pragma unroll
                for (int j = 0; j < 3; ++j) v += cmb[j][ct * 4 + r][wpos][lane];
                out[((size_t)n * COUT + co) * SP + spb + wpos * 16 + (lane & 15)] = v;
            }
    }
}

extern "C" void kernel_launch(void* const* d_in, const int* in_sizes, int n_in,
                              void* d_out, int out_size, void* d_ws, size_t ws_size,
                              hipStream_t stream) {
    const float* x    = (const float*)d_in[0];
    const float* off  = (const float*)d_in[1];
    const float* w    = (const float*)d_in[2];
    const float* bias = (const float*)d_in[3];
    float* out        = (float*)d_out;

    __half* wf  = (__half*)((char*)d_ws + WF_OFF);
    __half* xTh = (__half*)((char*)d_ws + XTH_OFF);

    prep_kernel<<<NBLKP + KK, 256, 0, stream>>>(x, w, xTh, wf);
    dconv3d_kernel<<<NBLK, 512, 0, stream>>>(xTh, off, wf, bias, out);
}